// Round 12
// baseline (167.631 us; speedup 1.0000x reference)
//
#include <hip/hip_runtime.h>
#include <hip/hip_bf16.h>
#include <hip/hip_cooperative_groups.h>

namespace cg = cooperative_groups;

#define NGRAPH 32
#define NHEAD 8
#define EMB 512
#define NNODES 16384
#define NPG 512
#define LQ 1024
#define PST 520     // padded LDS row stride (ushorts)
#define GCH 262144  // per-graph chunked slab (ushorts): 16 chunks * 512 rows * 32

typedef __attribute__((ext_vector_type(8))) short short8;
typedef __attribute__((ext_vector_type(4))) float f32x4;

static __device__ __forceinline__ unsigned short f2bf(float f) {
  union { float f; unsigned u; } v; v.f = f;
  unsigned r = (v.u + 0x7fffu + ((v.u >> 16) & 1u)) >> 16;
  return (unsigned short)r;
}

static __device__ __forceinline__ short8 cvt8(float4 a, float4 b) {
  short8 r;
  r[0] = f2bf(a.x); r[1] = f2bf(a.y); r[2] = f2bf(a.z); r[3] = f2bf(a.w);
  r[4] = f2bf(b.x); r[5] = f2bf(b.y); r[6] = f2bf(b.z); r[7] = f2bf(b.w);
  return r;
}

static __device__ __forceinline__ void gload_lds16(const ushort* g, ushort* l) {
  __builtin_amdgcn_global_load_lds(
      (const __attribute__((address_space(1))) unsigned*)g,
      (__attribute__((address_space(3))) unsigned*)l, 16, 0, 0);
}

#define BARRIER_LGKM()                                        \
  do {                                                        \
    asm volatile("s_waitcnt lgkmcnt(0)" ::: "memory");        \
    __builtin_amdgcn_s_barrier();                             \
  } while (0)

struct SmemA {
  ushort PCl[32 * PST];
  ushort PBuf[32 * PST];
  ushort Bbuf[2][16384];
  float rmax[32][16];
  float rsum[32][16];
};
union SmemU {
  SmemA a;
  ushort prep[4][11776];   // 4 sub-units x 23 KB
};

// =====================================================================
// mega: prep -> grid.sync -> fused attention -> grid.sync -> out_proj
// 256 blocks x 1024 threads, co-resident (cooperative launch).
// Block->XCD = b%8 is FIXED across phases: prep block b produces graphs
// g ≡ b (mod 8); attn block b consumes g = b&31 (same residue). [XCD pin]
// =====================================================================
__global__ __launch_bounds__(1024) void mega(
    const float* __restrict__ x, const float* __restrict__ wv,
    const float* __restrict__ wo, const float* __restrict__ wq,
    const float* __restrict__ wk, const float* __restrict__ xc,
    const float* __restrict__ bq, const float* __restrict__ bvb,
    const float* __restrict__ bob,
    ushort* __restrict__ xbC, ushort* __restrict__ xbTC,
    ushort* __restrict__ wvb, ushort* __restrict__ wob,
    ushort* __restrict__ PCb, ushort* __restrict__ aout,
    float* __restrict__ outf, float* __restrict__ bcent) {
  __shared__ __align__(16) SmemU sm;
  cg::grid_group grid = cg::this_grid();
  const int b = blockIdx.x;
  const int t = threadIdx.x;
  const int s = t >> 8, t256 = t & 255;
  ushort* ps = sm.prep[s];

  // ========== P1: x relayout — every block: 4 units (r10 code, verbatim) ====
  // unit (g, r2): g = (b&7) + 8*(b>>6); r2 = ((b>>3)&7)*4 + s.  Bijective.
  {
    const int g = (b & 7) + 8 * (b >> 6);
    const int r2 = ((b >> 3) & 7) * 4 + s;
    ushort* tileA = ps;            // [64][72]
    ushort* tileB = ps + 4608;     // [64][72]
    const int bc = r2 & 7;         // e-tile (e0 = bc*64)
    const int bl = r2 >> 3;        // n-slab of 128
    const int n0 = bl * 128, e0 = bc * 64;
    const int trr = t256 >> 4, tc = t256 & 15;

    float4 vA[4], vB[4];
#pragma unroll
    for (int p = 0; p < 4; ++p)
      vA[p] = *reinterpret_cast<const float4*>(
          x + (long)(g * NPG + n0 + trr + p * 16) * EMB + e0 + tc * 4);
#pragma unroll
    for (int p = 0; p < 4; ++p)
      vB[p] = *reinterpret_cast<const float4*>(
          x + (long)(g * NPG + n0 + 64 + trr + p * 16) * EMB + e0 + tc * 4);
#pragma unroll
    for (int p = 0; p < 4; ++p) {
      int n = trr + p * 16;
      ushort4 o;
      o.x = f2bf(vA[p].x); o.y = f2bf(vA[p].y); o.z = f2bf(vA[p].z); o.w = f2bf(vA[p].w);
      *reinterpret_cast<ushort4*>(&tileA[n * 72 + tc * 4]) = o;
    }
#pragma unroll
    for (int p = 0; p < 4; ++p) {
      int n = trr + p * 16;
      ushort4 o;
      o.x = f2bf(vB[p].x); o.y = f2bf(vB[p].y); o.z = f2bf(vB[p].z); o.w = f2bf(vB[p].w);
      *reinterpret_cast<ushort4*>(&tileB[n * 72 + tc * 4]) = o;
    }
    __syncthreads();   // [sync 1 — uniform across all 4 subs in every block]

    // xbC: contiguous 16B stores, swizzled source part
    {
      int n = t256 >> 2, pp = t256 & 3;
#pragma unroll
      for (int tb = 0; tb < 2; ++tb) {
        const ushort* tile = tb ? tileB : tileA;
        int ng = n0 + tb * 64 + n;
        int sp = pp ^ ((ng >> 1) & 3);
#pragma unroll
        for (int kcq = 0; kcq < 2; ++kcq) {
          int kc = bc * 2 + kcq;
          short8 v = *reinterpret_cast<const short8*>(&tile[n * 72 + kcq * 32 + sp * 8]);
          *reinterpret_cast<short8*>(
              &xbC[(long)g * GCH + kc * 16384 + ng * 32 + pp * 8]) = v;
        }
      }
    }
    // xbTC: jj-rotated gather, contiguous stores
    {
      int e = t256 >> 2;
      int eg = e0 + e;
      int sp2 = (t256 & 3) ^ ((eg >> 1) & 3);
      int rot = t256 & 7;
#pragma unroll
      for (int tb = 0; tb < 2; ++tb) {
        const ushort* tile = tb ? tileB : tileA;
#pragma unroll
        for (int ncq = 0; ncq < 2; ++ncq) {
          int nc = bl * 4 + tb * 2 + ncq;
          ushort tmp[8];
#pragma unroll
          for (int k = 0; k < 8; ++k) {
            int jj = (k + rot) & 7;
            tmp[jj] = tile[(ncq * 32 + sp2 * 8 + jj) * 72 + e];
          }
          *reinterpret_cast<short8*>(
              &xbTC[(long)g * GCH + nc * 16384 + eg * 32 + (t256 & 3) * 8]) =
              *reinterpret_cast<short8*>(tmp);
        }
      }
    }
  }
  __syncthreads();   // LDS handoff P1 -> P2 (uniform in every block)

  // ========== P2: qpc (b<8) / weight conv (8<=b<136) / batchcent (136) =====
  if (b < 8) {
    // qpc unit: h = b, qs = s  (1 sync inside — all 4 subs aligned)
    ushort* Qs  = ps;            // [32][72]
    ushort* WkT = ps + 2304;     // [128][72]
    const int h = b, qs = s;
    const int w = t256 >> 6, lane = t256 & 63;
    const int lr = lane & 15, grp = lane >> 4, ko = grp * 8;

    {
      int dl = t256 >> 2, cq = t256 & 3;
      const float* wr = wk + (long)(h * 64 + dl) * EMB + qs * 128;
#pragma unroll
      for (int m = 0; m < 8; ++m) {
        int c0 = cq * 32 + m * 4;
        float4 v = *reinterpret_cast<const float4*>(wr + c0);
        WkT[(c0 + 0) * 72 + dl] = f2bf(0.125f * v.x);
        WkT[(c0 + 1) * 72 + dl] = f2bf(0.125f * v.y);
        WkT[(c0 + 2) * 72 + dl] = f2bf(0.125f * v.z);
        WkT[(c0 + 3) * 72 + dl] = f2bf(0.125f * v.w);
      }
    }
    f32x4 qa[2];
    qa[0] = (f32x4)(0.0f); qa[1] = (f32x4)(0.0f);
#pragma unroll 4
    for (int kk = 0; kk < EMB; kk += 32) {
      const float* xr0 = xc + lr * EMB + kk + ko;
      const float* xr1 = xc + (16 + lr) * EMB + kk + ko;
      const float* wr  = wq + (long)(h * 64 + w * 16 + lr) * EMB + kk + ko;
      short8 a0 = cvt8(*reinterpret_cast<const float4*>(xr0),
                       *reinterpret_cast<const float4*>(xr0 + 4));
      short8 a1 = cvt8(*reinterpret_cast<const float4*>(xr1),
                       *reinterpret_cast<const float4*>(xr1 + 4));
      short8 bb = cvt8(*reinterpret_cast<const float4*>(wr),
                       *reinterpret_cast<const float4*>(wr + 4));
      qa[0] = __builtin_amdgcn_mfma_f32_16x16x32_bf16(a0, bb, qa[0], 0, 0, 0);
      qa[1] = __builtin_amdgcn_mfma_f32_16x16x32_bf16(a1, bb, qa[1], 0, 0, 0);
    }
    float bias = bq[h * 64 + w * 16 + lr];
#pragma unroll
    for (int i = 0; i < 2; ++i)
#pragma unroll
      for (int r = 0; r < 4; ++r)
        Qs[(i * 16 + grp * 4 + r) * 72 + w * 16 + lr] = f2bf(qa[i][r] + bias);
    __syncthreads();

    f32x4 pa[2][2];
#pragma unroll
    for (int i = 0; i < 2; ++i)
#pragma unroll
      for (int j = 0; j < 2; ++j) pa[i][j] = (f32x4)(0.0f);
#pragma unroll
    for (int kk = 0; kk < 64; kk += 32) {
      short8 a0 = *reinterpret_cast<const short8*>(&Qs[lr * 72 + kk + ko]);
      short8 a1 = *reinterpret_cast<const short8*>(&Qs[(16 + lr) * 72 + kk + ko]);
#pragma unroll
      for (int j = 0; j < 2; ++j) {
        short8 bb = *reinterpret_cast<const short8*>(
            &WkT[(w * 32 + j * 16 + lr) * 72 + kk + ko]);
        pa[0][j] = __builtin_amdgcn_mfma_f32_16x16x32_bf16(a0, bb, pa[0][j], 0, 0, 0);
        pa[1][j] = __builtin_amdgcn_mfma_f32_16x16x32_bf16(a1, bb, pa[1][j], 0, 0, 0);
      }
    }
#pragma unroll
    for (int i = 0; i < 2; ++i)
#pragma unroll
      for (int j = 0; j < 2; ++j)
#pragma unroll
        for (int r = 0; r < 4; ++r)
          PCb[(long)(h * 32 + i * 16 + grp * 4 + r) * EMB + qs * 128 + w * 32 + j * 16 + lr] =
              f2bf(pa[i][j][r]);
  } else if (b < 136) {
    int off = (b - 8) * 4 + s;          // [0,512)
    const float* src = (off < 256) ? wv : wo;
    ushort* dst = (off < 256) ? wvb : wob;
    off &= 255;
    int i = (off * 256 + t256) * 4;
    float4 v = *reinterpret_cast<const float4*>(src + i);
    ushort4 o;
    o.x = f2bf(v.x); o.y = f2bf(v.y); o.z = f2bf(v.z); o.w = f2bf(v.w);
    *reinterpret_cast<ushort4*>(dst + i) = o;
  } else if (b == 136 && s == 0) {
#pragma unroll
    for (int p = 0; p < 4; ++p) bcent[t256 + p * 256] = (float)((t256 + p * 256) >> 5);
  }

  grid.sync();   // prep outputs visible device-wide

  // ========== A: fused attention, block b = (g = b&31, h = b>>5) ===========
  {
    const int g = b & 31, h = b >> 5;
    const int w = t >> 6, lane = t & 63;
    const int lr = lane & 15, grp = lane >> 4;
    const int koU = grp * 8;

    const ushort* xgC  = xbC  + (long)g * GCH;
    const ushort* xgTC = xbTC + (long)g * GCH;

    auto STAGE1 = [&](int c, int db) {
#pragma unroll
      for (int q = 0; q < 2; ++q)
        gload_lds16(xgC + c * 16384 + (w * 32 + q * 16) * 32 + lane * 8,
                    &sm.a.Bbuf[db][(w * 32 + q * 16) * 32]);
    };
    auto STAGE3 = [&](int c, int db) {
#pragma unroll
      for (int q = 0; q < 2; ++q)
        gload_lds16(xgTC + c * 16384 + (w * 32 + q * 16) * 32 + lane * 8,
                    &sm.a.Bbuf[db][(w * 32 + q * 16) * 32]);
    };

    STAGE1(0, 0);
    STAGE1(1, 1);
    {
      const ushort* pc = PCb + h * 32 * EMB;
#pragma unroll
      for (int p = 0; p < 2; ++p) {
        int u = t + p * 1024;
        int row = u >> 6, col = (u & 63) * 8;
        *reinterpret_cast<short8*>(&sm.a.PCl[row * PST + col]) =
            *reinterpret_cast<const short8*>(pc + row * EMB + col);
      }
    }
    BARRIER_LGKM();

    // phase 1: S = PC_h · X_g^T
    f32x4 acc[2][2];
#pragma unroll
    for (int i = 0; i < 2; ++i)
#pragma unroll
      for (int j = 0; j < 2; ++j) acc[i][j] = (f32x4)(0.0f);

#pragma unroll
    for (int c = 0; c < 16; ++c) {
      const int db = c & 1;
      asm volatile("s_waitcnt vmcnt(2)" ::: "memory");
      __builtin_amdgcn_sched_barrier(0);
      short8 a0 = *reinterpret_cast<const short8*>(&sm.a.PCl[lr * PST + c * 32 + koU]);
      short8 a1 = *reinterpret_cast<const short8*>(&sm.a.PCl[(16 + lr) * PST + c * 32 + koU]);
      short8 bv8[2];
#pragma unroll
      for (int j = 0; j < 2; ++j) {
        int n = w * 32 + j * 16 + lr;
        int psrc = grp ^ ((n >> 1) & 3);
        bv8[j] = *reinterpret_cast<const short8*>(&sm.a.Bbuf[db][n * 32 + psrc * 8]);
      }
#pragma unroll
      for (int j = 0; j < 2; ++j) {
        acc[0][j] = __builtin_amdgcn_mfma_f32_16x16x32_bf16(a0, bv8[j], acc[0][j], 0, 0, 0);
        acc[1][j] = __builtin_amdgcn_mfma_f32_16x16x32_bf16(a1, bv8[j], acc[1][j], 0, 0, 0);
      }
      __builtin_amdgcn_sched_barrier(0);
      if (c < 14) STAGE1(c + 2, db);
      else        STAGE3(c - 14, db);
    }

    // phase 2: softmax
#pragma unroll
    for (int i = 0; i < 2; ++i)
#pragma unroll
      for (int r = 0; r < 4; ++r) {
        float m = fmaxf(acc[i][0][r], acc[i][1][r]);
        m = fmaxf(m, __shfl_xor(m, 1)); m = fmaxf(m, __shfl_xor(m, 2));
        m = fmaxf(m, __shfl_xor(m, 4)); m = fmaxf(m, __shfl_xor(m, 8));
        if (lr == 0) sm.a.rmax[i * 16 + grp * 4 + r][w] = m;
      }
    BARRIER_LGKM();
#pragma unroll
    for (int i = 0; i < 2; ++i)
#pragma unroll
      for (int r = 0; r < 4; ++r) {
        int row = i * 16 + grp * 4 + r;
        float m = sm.a.rmax[row][0];
#pragma unroll
        for (int q = 1; q < 16; ++q) m = fmaxf(m, sm.a.rmax[row][q]);
        float ssum = 0.f;
#pragma unroll
        for (int j = 0; j < 2; ++j) {
          float e = __expf(acc[i][j][r] - m);
          acc[i][j][r] = e;
          ssum += e;
        }
        ssum += __shfl_xor(ssum, 1); ssum += __shfl_xor(ssum, 2);
        ssum += __shfl_xor(ssum, 4); ssum += __shfl_xor(ssum, 8);
        if (lr == 0) sm.a.rsum[row][w] = ssum;
      }
    BARRIER_LGKM();
#pragma unroll
    for (int i = 0; i < 2; ++i)
#pragma unroll
      for (int r = 0; r < 4; ++r) {
        int row = i * 16 + grp * 4 + r;
        float tot = sm.a.rsum[row][0];
#pragma unroll
        for (int q = 1; q < 16; ++q) tot += sm.a.rsum[row][q];
        float inv = 1.f / tot;
#pragma unroll
        for (int j = 0; j < 2; ++j)
          sm.a.PBuf[row * PST + w * 32 + j * 16 + lr] = f2bf(acc[i][j][r] * inv);
      }
    BARRIER_LGKM();

    // phase 3: R = attn · X_g
    f32x4 acc2[2][2];
#pragma unroll
    for (int i = 0; i < 2; ++i)
#pragma unroll
      for (int j = 0; j < 2; ++j) acc2[i][j] = (f32x4)(0.0f);

#pragma unroll
    for (int c = 0; c < 16; ++c) {
      const int db = c & 1;
      if (c < 15) asm volatile("s_waitcnt vmcnt(2)" ::: "memory");
      else        asm volatile("s_waitcnt vmcnt(0)" ::: "memory");
      __builtin_amdgcn_sched_barrier(0);
      short8 a0 = *reinterpret_cast<const short8*>(&sm.a.PBuf[lr * PST + c * 32 + koU]);
      short8 a1 = *reinterpret_cast<const short8*>(&sm.a.PBuf[(16 + lr) * PST + c * 32 + koU]);
      short8 bv8[2];
#pragma unroll
      for (int j = 0; j < 2; ++j) {
        int e = w * 32 + j * 16 + lr;
        int psrc = grp ^ ((e >> 1) & 3);
        bv8[j] = *reinterpret_cast<const short8*>(&sm.a.Bbuf[db][e * 32 + psrc * 8]);
      }
#pragma unroll
      for (int j = 0; j < 2; ++j) {
        acc2[0][j] = __builtin_amdgcn_mfma_f32_16x16x32_bf16(a0, bv8[j], acc2[0][j], 0, 0, 0);
        acc2[1][j] = __builtin_amdgcn_mfma_f32_16x16x32_bf16(a1, bv8[j], acc2[1][j], 0, 0, 0);
      }
      __builtin_amdgcn_sched_barrier(0);
      if (c < 14) STAGE3(c + 2, db);
    }
    BARRIER_LGKM();

#pragma unroll
    for (int i = 0; i < 2; ++i)
#pragma unroll
      for (int r = 0; r < 4; ++r) {
        int row = i * 16 + grp * 4 + r;
#pragma unroll
        for (int j = 0; j < 2; ++j)
          sm.a.PBuf[row * PST + w * 32 + j * 16 + lr] = f2bf(acc2[i][j][r]);
      }
    BARRIER_LGKM();

    // phase 4: aout_h = R · wv_h^T + bv_h (waves 0..7)
    if (w < 8) {
      int wr = w >> 2, wc = w & 3;
      f32x4 acc3 = (f32x4)(0.0f);
      const ushort* wvh = wvb + (long)(h * 64 + wc * 16) * EMB;
#pragma unroll
      for (int c = 0; c < 16; ++c) {
        short8 a = *reinterpret_cast<const short8*>(&sm.a.PBuf[(wr * 16 + lr) * PST + c * 32 + koU]);
        short8 bb = *reinterpret_cast<const short8*>(wvh + (long)lr * EMB + c * 32 + koU);
        acc3 = __builtin_amdgcn_mfma_f32_16x16x32_bf16(a, bb, acc3, 0, 0, 0);
      }
      float bias = bvb[h * 64 + wc * 16 + lr];
#pragma unroll
      for (int r = 0; r < 4; ++r) {
        int row = wr * 16 + grp * 4 + r;
        aout[(long)(g * 32 + row) * EMB + h * 64 + wc * 16 + lr] = f2bf(acc3[r] + bias);
      }
    }
  }

  grid.sync();   // aout visible device-wide

  // ========== G: out_proj — block b -> 32x64 tile, 8 waves, 2-way K split ==
  {
    float* gacc = (float*)sm.a.PBuf;   // 32*64 f32 partials (8 KB)
    const int bx = b & 7, by = b >> 3;
    const int wave = t >> 6, lane = t & 63;
    const int lr = lane & 15, ko = (lane >> 4) * 8;
    const int kg = wave >> 2, w4 = wave & 3;
    const int wr = w4 >> 1, wc = w4 & 1;
    const int rowBase = by * 32 + wr * 16;
    const int colBase = bx * 64 + wc * 32;
    f32x4 acc0 = (f32x4)(0.0f), acc1 = (f32x4)(0.0f);
    if (wave < 8) {
#pragma unroll 4
      for (int kk = kg * 256; kk < kg * 256 + 256; kk += 32) {
        short8 av = *reinterpret_cast<const short8*>(aout + (long)(rowBase + lr) * EMB + kk + ko);
        short8 b0 = *reinterpret_cast<const short8*>(wob + (long)(colBase + lr) * EMB + kk + ko);
        short8 b1 = *reinterpret_cast<const short8*>(wob + (long)(colBase + 16 + lr) * EMB + kk + ko);
        acc0 = __builtin_amdgcn_mfma_f32_16x16x32_bf16(av, b0, acc0, 0, 0, 0);
        acc1 = __builtin_amdgcn_mfma_f32_16x16x32_bf16(av, b1, acc1, 0, 0, 0);
      }
      if (kg == 1) {
        int or0 = (lane >> 4) * 4;
#pragma unroll
        for (int r = 0; r < 4; ++r) {
          gacc[(wr * 16 + or0 + r) * 64 + wc * 32 + lr] = acc0[r];
          gacc[(wr * 16 + or0 + r) * 64 + wc * 32 + 16 + lr] = acc1[r];
        }
      }
    }
    __syncthreads();
    if (wave < 4) {
      int or0 = (lane >> 4) * 4;
#pragma unroll
      for (int r = 0; r < 4; ++r) {
        int lrow = wr * 16 + or0 + r;
        int c0 = wc * 32 + lr, c1 = c0 + 16;
        outf[(long)(by * 32 + lrow) * EMB + bx * 64 + c0] =
            acc0[r] + gacc[lrow * 64 + c0] + bob[bx * 64 + c0];
        outf[(long)(by * 32 + lrow) * EMB + bx * 64 + c1] =
            acc1[r] + gacc[lrow * 64 + c1] + bob[bx * 64 + c1];
      }
    }
  }
}

extern "C" void kernel_launch(void* const* d_in, const int* in_sizes, int n_in,
                              void* d_out, int out_size, void* d_ws, size_t ws_size,
                              hipStream_t stream) {
  const float* x          = (const float*)d_in[0];
  const float* xc         = (const float*)d_in[3];
  const float* in_proj_w  = (const float*)d_in[4];
  const float* in_proj_b  = (const float*)d_in[5];
  const float* wo         = (const float*)d_in[6];
  const float* bob        = (const float*)d_in[7];

  char* w = (char*)d_ws;
  ushort* xbC  = (ushort*)(w);                 // 16 MiB
  ushort* xbTC = (ushort*)(w + 16777216);      // 16 MiB
  ushort* PCb  = (ushort*)(w + 33554432);      // 256 KiB
  ushort* wvb  = (ushort*)(w + 33816576);      // 512 KiB
  ushort* wob  = (ushort*)(w + 34340864);      // 512 KiB
  ushort* aout = (ushort*)(w + 34865152);      // 1 MiB

  const float* wq  = in_proj_w;
  const float* wk  = in_proj_w + 512 * 512;
  const float* wv  = in_proj_w + 1024 * 512;
  const float* bq  = in_proj_b;
  const float* bvb = in_proj_b + 1024;
  float* outf  = (float*)d_out;
  float* bcent = (float*)d_out + (long)LQ * EMB;

  void* args[] = {
      (void*)&x,   (void*)&wv,  (void*)&wo,   (void*)&wq,  (void*)&wk,
      (void*)&xc,  (void*)&bq,  (void*)&bvb,  (void*)&bob,
      (void*)&xbC, (void*)&xbTC,(void*)&wvb,  (void*)&wob, (void*)&PCb,
      (void*)&aout,(void*)&outf,(void*)&bcent};

  hipLaunchCooperativeKernel((const void*)mega, dim3(256), dim3(1024),
                             args, 0, stream);
}

// Round 13
// 57.575 us; speedup vs baseline: 2.9115x; 2.9115x over previous
//
#include <hip/hip_runtime.h>
#include <hip/hip_bf16.h>

#define NGRAPH 32
#define NHEAD 8
#define EMB 512
#define NNODES 16384
#define NPG 512
#define LQ 1024
#define PST 520   // padded LDS row stride (ushorts): quad-aligned, 2-way (free)
#define GCH 262144  // per-graph chunked-slab size in ushorts (16 chunks * 512 rows * 32)

typedef __attribute__((ext_vector_type(8))) short short8;
typedef __attribute__((ext_vector_type(4))) float f32x4;

static __device__ __forceinline__ unsigned short f2bf(float f) {
  union { float f; unsigned u; } v; v.f = f;
  unsigned r = (v.u + 0x7fffu + ((v.u >> 16) & 1u)) >> 16;
  return (unsigned short)r;
}

static __device__ __forceinline__ short8 cvt8(float4 a, float4 b) {
  short8 r;
  r[0] = f2bf(a.x); r[1] = f2bf(a.y); r[2] = f2bf(a.z); r[3] = f2bf(a.w);
  r[4] = f2bf(b.x); r[5] = f2bf(b.y); r[6] = f2bf(b.z); r[7] = f2bf(b.w);
  return r;
}

// async global->LDS: global src is PER-LANE, LDS dest = uniform base + lane*16
static __device__ __forceinline__ void gload_lds16(const ushort* g, ushort* l) {
  __builtin_amdgcn_global_load_lds(
      (const __attribute__((address_space(1))) unsigned*)g,
      (__attribute__((address_space(3))) unsigned*)l, 16, 0, 0);
}

// lgkm-only barrier: does NOT drain vmcnt -> global_load_lds prefetches survive
#define BARRIER_LGKM()                                        \
  do {                                                        \
    asm volatile("s_waitcnt lgkmcnt(0)" ::: "memory");        \
    __builtin_amdgcn_s_barrier();                             \
  } while (0)

// =====================================================================
// prep_all (grid 1576):
//   [0,32)      : qpc (overlaps streaming) -> PCb
//   [32,544)    : wv -> wvb ; wo -> wob   (moved off the tail)
//   544         : batchcent ; [545,552) idle pad (keeps x 8-aligned)
//   [552,1576)  : x f32 -> xbC / xbTC ; 128x64 slab per block
//                 (local%8 == g%8 -> graph g produced on XCD g%8)
// =====================================================================
__global__ __launch_bounds__(256) void prep_all(
    const float* __restrict__ x, const float* __restrict__ wv,
    const float* __restrict__ wo, const float* __restrict__ wq,
    const float* __restrict__ wk, const float* __restrict__ xc,
    const float* __restrict__ bq,
    ushort* __restrict__ xbC, ushort* __restrict__ xbTC,
    ushort* __restrict__ wvb, ushort* __restrict__ wob,
    ushort* __restrict__ PCb, float* __restrict__ bcent) {
  __shared__ ushort smemU[11776];   // 23 KB, carved per role
  const int b = blockIdx.x;
  const int t = threadIdx.x;

  if (b < 32) {
    // ---- qpc: PC[h*32+l, qs*128..+128] = (xc·wq_h^T + bq_h) · (0.125·wk_h) ----
    ushort* Qs  = smemU;            // [32][72]
    ushort* WkT = smemU + 2304;     // [128][72]
    int h = b >> 2, qs = b & 3;
    int w = t >> 6, lane = t & 63;
    int lr = lane & 15, grp = lane >> 4, ko = grp * 8;

    {
      int dl = t >> 2, cq = t & 3;
      const float* wr = wk + (long)(h * 64 + dl) * EMB + qs * 128;
#pragma unroll
      for (int m = 0; m < 8; ++m) {
        int c0 = cq * 32 + m * 4;
        float4 v = *reinterpret_cast<const float4*>(wr + c0);
        WkT[(c0 + 0) * 72 + dl] = f2bf(0.125f * v.x);
        WkT[(c0 + 1) * 72 + dl] = f2bf(0.125f * v.y);
        WkT[(c0 + 2) * 72 + dl] = f2bf(0.125f * v.z);
        WkT[(c0 + 3) * 72 + dl] = f2bf(0.125f * v.w);
      }
    }

    f32x4 qa[2];
    qa[0] = (f32x4)(0.0f); qa[1] = (f32x4)(0.0f);
#pragma unroll 4
    for (int kk = 0; kk < EMB; kk += 32) {
      const float* xr0 = xc + lr * EMB + kk + ko;
      const float* xr1 = xc + (16 + lr) * EMB + kk + ko;
      const float* wr  = wq + (long)(h * 64 + w * 16 + lr) * EMB + kk + ko;
      short8 a0 = cvt8(*reinterpret_cast<const float4*>(xr0),
                       *reinterpret_cast<const float4*>(xr0 + 4));
      short8 a1 = cvt8(*reinterpret_cast<const float4*>(xr1),
                       *reinterpret_cast<const float4*>(xr1 + 4));
      short8 bb = cvt8(*reinterpret_cast<const float4*>(wr),
                       *reinterpret_cast<const float4*>(wr + 4));
      qa[0] = __builtin_amdgcn_mfma_f32_16x16x32_bf16(a0, bb, qa[0], 0, 0, 0);
      qa[1] = __builtin_amdgcn_mfma_f32_16x16x32_bf16(a1, bb, qa[1], 0, 0, 0);
    }
    float bias = bq[h * 64 + w * 16 + lr];
#pragma unroll
    for (int i = 0; i < 2; ++i)
#pragma unroll
      for (int r = 0; r < 4; ++r)
        Qs[(i * 16 + grp * 4 + r) * 72 + w * 16 + lr] = f2bf(qa[i][r] + bias);
    __syncthreads();

    f32x4 pa[2][2];
#pragma unroll
    for (int i = 0; i < 2; ++i)
#pragma unroll
      for (int j = 0; j < 2; ++j) pa[i][j] = (f32x4)(0.0f);
#pragma unroll
    for (int kk = 0; kk < 64; kk += 32) {
      short8 a0 = *reinterpret_cast<const short8*>(&Qs[lr * 72 + kk + ko]);
      short8 a1 = *reinterpret_cast<const short8*>(&Qs[(16 + lr) * 72 + kk + ko]);
#pragma unroll
      for (int j = 0; j < 2; ++j) {
        short8 bb = *reinterpret_cast<const short8*>(
            &WkT[(w * 32 + j * 16 + lr) * 72 + kk + ko]);
        pa[0][j] = __builtin_amdgcn_mfma_f32_16x16x32_bf16(a0, bb, pa[0][j], 0, 0, 0);
        pa[1][j] = __builtin_amdgcn_mfma_f32_16x16x32_bf16(a1, bb, pa[1][j], 0, 0, 0);
      }
    }
#pragma unroll
    for (int i = 0; i < 2; ++i)
#pragma unroll
      for (int j = 0; j < 2; ++j)
#pragma unroll
        for (int r = 0; r < 4; ++r)
          PCb[(long)(h * 32 + i * 16 + grp * 4 + r) * EMB + qs * 128 + w * 32 + j * 16 + lr] =
              f2bf(pa[i][j][r]);
    return;
  }

  if (b < 544) {
    // ---- weight conversion (early: overlaps x streaming, no tail) ----
    int off = b - 32;
    const float* src = (off < 256) ? wv : wo;
    ushort* dst = (off < 256) ? wvb : wob;
    off &= 255;
    int i = (off * 256 + t) * 4;
    float4 v = *reinterpret_cast<const float4*>(src + i);
    ushort4 o;
    o.x = f2bf(v.x); o.y = f2bf(v.y); o.z = f2bf(v.z); o.w = f2bf(v.w);
    *reinterpret_cast<ushort4*>(dst + i) = o;
    return;
  }

  if (b == 544) {
#pragma unroll
    for (int p = 0; p < 4; ++p) bcent[t + p * 256] = (float)((t + p * 256) >> 5);
    return;
  }
  if (b < 552) return;   // pad to 8-align the x-blocks

  // ---- x slab: 128 nodes x 64 E of graph g (local%8 == g%8 -> XCD pinned) ----
  {
    ushort* tileA = smemU;            // [64][72]
    ushort* tileB = smemU + 4608;     // [64][72]
    int local = b - 552;
    int xr = local & 7, j = local >> 3;   // j 0..127
    int m = j >> 5, r = j & 31;
    int g = xr + 8 * m;
    int bc = r & 7;                   // e-tile (e0 = bc*64)
    int bl = r >> 3;                  // n-slab of 128 (0..3)
    int n0 = bl * 128, e0 = bc * 64;
    int trr = t >> 4, tc = t & 15;

    // issue all 8 loads up-front (32 KB in flight per block)
    float4 vA[4], vB[4];
#pragma unroll
    for (int p = 0; p < 4; ++p)
      vA[p] = *reinterpret_cast<const float4*>(
          x + (long)(g * NPG + n0 + trr + p * 16) * EMB + e0 + tc * 4);
#pragma unroll
    for (int p = 0; p < 4; ++p)
      vB[p] = *reinterpret_cast<const float4*>(
          x + (long)(g * NPG + n0 + 64 + trr + p * 16) * EMB + e0 + tc * 4);
#pragma unroll
    for (int p = 0; p < 4; ++p) {
      int n = trr + p * 16;
      ushort4 o;
      o.x = f2bf(vA[p].x); o.y = f2bf(vA[p].y); o.z = f2bf(vA[p].z); o.w = f2bf(vA[p].w);
      *reinterpret_cast<ushort4*>(&tileA[n * 72 + tc * 4]) = o;
    }
#pragma unroll
    for (int p = 0; p < 4; ++p) {
      int n = trr + p * 16;
      ushort4 o;
      o.x = f2bf(vB[p].x); o.y = f2bf(vB[p].y); o.z = f2bf(vB[p].z); o.w = f2bf(vB[p].w);
      *reinterpret_cast<ushort4*>(&tileB[n * 72 + tc * 4]) = o;
    }
    __syncthreads();

    // xbC: kc = e-chunk; contiguous 16B stores, swizzled source part
    {
      int n = t >> 2, pp = t & 3;
#pragma unroll
      for (int tb = 0; tb < 2; ++tb) {
        const ushort* tile = tb ? tileB : tileA;
        int ng = n0 + tb * 64 + n;
        int sp = pp ^ ((ng >> 1) & 3);
#pragma unroll
        for (int kcq = 0; kcq < 2; ++kcq) {
          int kc = bc * 2 + kcq;
          short8 v = *reinterpret_cast<const short8*>(&tile[n * 72 + kcq * 32 + sp * 8]);
          *reinterpret_cast<short8*>(
              &xbC[(long)g * GCH + kc * 16384 + ng * 32 + pp * 8]) = v;
        }
      }
    }
    // xbTC: nc = node-chunk; jj-rotated gather (bank-spread), contiguous stores
    {
      int e = t >> 2;
      int eg = e0 + e;
      int sp2 = (t & 3) ^ ((eg >> 1) & 3);
      int rot = t & 7;
#pragma unroll
      for (int tb = 0; tb < 2; ++tb) {
        const ushort* tile = tb ? tileB : tileA;
#pragma unroll
        for (int ncq = 0; ncq < 2; ++ncq) {
          int nc = bl * 4 + tb * 2 + ncq;
          ushort tmp[8];
#pragma unroll
          for (int k = 0; k < 8; ++k) {
            int jj = (k + rot) & 7;
            tmp[jj] = tile[(ncq * 32 + sp2 * 8 + jj) * 72 + e];
          }
          *reinterpret_cast<short8*>(
              &xbTC[(long)g * GCH + nc * 16384 + eg * 32 + (t & 3) * 8]) =
              *reinterpret_cast<short8*>(tmp);
        }
      }
    }
  }
}

// =====================================================================
// fused_attn: per (graph, head); 16 waves; barrier-free K-loops with
// fully-coalesced 1KB global_load_lds (per-lane src = base + lane*16B).
// =====================================================================
__global__ __launch_bounds__(1024) void fused_attn(
    const ushort* __restrict__ PCb, const ushort* __restrict__ xbC,
    const ushort* __restrict__ xbTC, const ushort* __restrict__ wvb,
    const float* __restrict__ bvb, ushort* __restrict__ aout) {
  __shared__ ushort PCl[32 * PST];
  __shared__ ushort PBuf[32 * PST];
  __shared__ ushort Bbuf[2][16384];   // [buf][512 rows][32]
  __shared__ float rmax[32][16];
  __shared__ float rsum[32][16];

  const int g = blockIdx.x & 31, h = blockIdx.x >> 5;  // g%8 == blk%8 -> XCD pinning
  const int t = threadIdx.x, w = t >> 6, lane = t & 63;
  const int lr = lane & 15, grp = lane >> 4;
  const int koU = grp * 8;

  const ushort* xgC  = xbC  + (long)g * GCH;
  const ushort* xgTC = xbTC + (long)g * GCH;

  auto STAGE1 = [&](int c, int db) {
#pragma unroll
    for (int q = 0; q < 2; ++q)
      gload_lds16(xgC + c * 16384 + (w * 32 + q * 16) * 32 + lane * 8,
                  &Bbuf[db][(w * 32 + q * 16) * 32]);
  };
  auto STAGE3 = [&](int c, int db) {
#pragma unroll
    for (int q = 0; q < 2; ++q)
      gload_lds16(xgTC + c * 16384 + (w * 32 + q * 16) * 32 + lane * 8,
                  &Bbuf[db][(w * 32 + q * 16) * 32]);
  };

  STAGE1(0, 0);
  STAGE1(1, 1);
  // stage PC_h into padded LDS
  {
    const ushort* pc = PCb + h * 32 * EMB;
#pragma unroll
    for (int p = 0; p < 2; ++p) {
      int u = t + p * 1024;
      int row = u >> 6, col = (u & 63) * 8;
      *reinterpret_cast<short8*>(&PCl[row * PST + col]) =
          *reinterpret_cast<const short8*>(pc + row * EMB + col);
    }
  }
  BARRIER_LGKM();

  // ---------- phase 1: S = PC_h · X_g^T ; NO barriers ----------
  f32x4 acc[2][2];
#pragma unroll
  for (int i = 0; i < 2; ++i)
#pragma unroll
    for (int j = 0; j < 2; ++j) acc[i][j] = (f32x4)(0.0f);

#pragma unroll
  for (int c = 0; c < 16; ++c) {
    const int db = c & 1;
    asm volatile("s_waitcnt vmcnt(2)" ::: "memory");
    __builtin_amdgcn_sched_barrier(0);
    short8 a0 = *reinterpret_cast<const short8*>(&PCl[lr * PST + c * 32 + koU]);
    short8 a1 = *reinterpret_cast<const short8*>(&PCl[(16 + lr) * PST + c * 32 + koU]);
    short8 bv8[2];
#pragma unroll
    for (int j = 0; j < 2; ++j) {
      int n = w * 32 + j * 16 + lr;
      int psrc = grp ^ ((n >> 1) & 3);
      bv8[j] = *reinterpret_cast<const short8*>(&Bbuf[db][n * 32 + psrc * 8]);
    }
#pragma unroll
    for (int j = 0; j < 2; ++j) {
      acc[0][j] = __builtin_amdgcn_mfma_f32_16x16x32_bf16(a0, bv8[j], acc[0][j], 0, 0, 0);
      acc[1][j] = __builtin_amdgcn_mfma_f32_16x16x32_bf16(a1, bv8[j], acc[1][j], 0, 0, 0);
    }
    __builtin_amdgcn_sched_barrier(0);
    if (c < 14) STAGE1(c + 2, db);
    else        STAGE3(c - 14, db);
  }

  // ---------- phase 2: softmax (cols split 16 ways) ----------
#pragma unroll
  for (int i = 0; i < 2; ++i)
#pragma unroll
    for (int r = 0; r < 4; ++r) {
      float m = fmaxf(acc[i][0][r], acc[i][1][r]);
      m = fmaxf(m, __shfl_xor(m, 1)); m = fmaxf(m, __shfl_xor(m, 2));
      m = fmaxf(m, __shfl_xor(m, 4)); m = fmaxf(m, __shfl_xor(m, 8));
      if (lr == 0) rmax[i * 16 + grp * 4 + r][w] = m;
    }
  BARRIER_LGKM();
#pragma unroll
  for (int i = 0; i < 2; ++i)
#pragma unroll
    for (int r = 0; r < 4; ++r) {
      int row = i * 16 + grp * 4 + r;
      float m = rmax[row][0];
#pragma unroll
      for (int q = 1; q < 16; ++q) m = fmaxf(m, rmax[row][q]);
      float s = 0.f;
#pragma unroll
      for (int j = 0; j < 2; ++j) {
        float e = __expf(acc[i][j][r] - m);
        acc[i][j][r] = e;
        s += e;
      }
      s += __shfl_xor(s, 1); s += __shfl_xor(s, 2);
      s += __shfl_xor(s, 4); s += __shfl_xor(s, 8);
      if (lr == 0) rsum[row][w] = s;
    }
  BARRIER_LGKM();
#pragma unroll
  for (int i = 0; i < 2; ++i)
#pragma unroll
    for (int r = 0; r < 4; ++r) {
      int row = i * 16 + grp * 4 + r;
      float tot = rsum[row][0];
#pragma unroll
      for (int q = 1; q < 16; ++q) tot += rsum[row][q];
      float inv = 1.f / tot;
#pragma unroll
      for (int j = 0; j < 2; ++j)
        PBuf[row * PST + w * 32 + j * 16 + lr] = f2bf(acc[i][j][r] * inv);
    }
  BARRIER_LGKM();   // attn ready in PBuf

  // ---------- phase 3: R = attn · X_g ; NO barriers ----------
  f32x4 acc2[2][2];
#pragma unroll
  for (int i = 0; i < 2; ++i)
#pragma unroll
    for (int j = 0; j < 2; ++j) acc2[i][j] = (f32x4)(0.0f);

#pragma unroll
  for (int c = 0; c < 16; ++c) {
    const int db = c & 1;
    if (c < 15) asm volatile("s_waitcnt vmcnt(2)" ::: "memory");
    else        asm volatile("s_waitcnt vmcnt(0)" ::: "memory");
    __builtin_amdgcn_sched_barrier(0);
    short8 a0 = *reinterpret_cast<const short8*>(&PBuf[lr * PST + c * 32 + koU]);
    short8 a1 = *reinterpret_cast<const short8*>(&PBuf[(16 + lr) * PST + c * 32 + koU]);
    short8 bv8[2];
#pragma unroll
    for (int j = 0; j < 2; ++j) {
      int e = w * 32 + j * 16 + lr;
      int psrc = grp ^ ((e >> 1) & 3);
      bv8[j] = *reinterpret_cast<const short8*>(&Bbuf[db][e * 32 + psrc * 8]);
    }
#pragma unroll
    for (int j = 0; j < 2; ++j) {
      acc2[0][j] = __builtin_amdgcn_mfma_f32_16x16x32_bf16(a0, bv8[j], acc2[0][j], 0, 0, 0);
      acc2[1][j] = __builtin_amdgcn_mfma_f32_16x16x32_bf16(a1, bv8[j], acc2[1][j], 0, 0, 0);
    }
    __builtin_amdgcn_sched_barrier(0);
    if (c < 14) STAGE3(c + 2, db);
  }
  BARRIER_LGKM();   // all waves done reading attn in PBuf

  // write R into PBuf
#pragma unroll
  for (int i = 0; i < 2; ++i)
#pragma unroll
    for (int r = 0; r < 4; ++r) {
      int row = i * 16 + grp * 4 + r;
#pragma unroll
      for (int j = 0; j < 2; ++j)
        PBuf[row * PST + w * 32 + j * 16 + lr] = f2bf(acc2[i][j][r]);
    }
  BARRIER_LGKM();   // R ready

  // ---------- phase 4: aout_h = R · wv_h^T + bv_h  (waves 0..7) ----------
  if (w < 8) {
    int wr = w >> 2, wc = w & 3;
    f32x4 acc3 = (f32x4)(0.0f);
    const ushort* wvh = wvb + (long)(h * 64 + wc * 16) * EMB;
#pragma unroll
    for (int c = 0; c < 16; ++c) {
      short8 a = *reinterpret_cast<const short8*>(&PBuf[(wr * 16 + lr) * PST + c * 32 + koU]);
      short8 b = *reinterpret_cast<const short8*>(wvh + (long)lr * EMB + c * 32 + koU);
      acc3 = __builtin_amdgcn_mfma_f32_16x16x32_bf16(a, b, acc3, 0, 0, 0);
    }
    float bias = bvb[h * 64 + wc * 16 + lr];
#pragma unroll
    for (int r = 0; r < 4; ++r) {
      int row = wr * 16 + grp * 4 + r;
      aout[(long)(g * 32 + row) * EMB + h * 64 + wc * 16 + lr] = f2bf(acc3[r] + bias);
    }
  }
}

// ---- out_proj GEMM. Row tile on blockIdx.x so flat%8 == row-tile%8 ==
// the XCD where fused_attn produced those aout rows (g = row-tile). ----
template <int KK, int FM, int FN, int WM, int WN, bool OUT_BF16, bool HAS_BIAS>
__global__ void gemm_abt(const ushort* __restrict__ A, const ushort* __restrict__ Bm,
                         void* __restrict__ C, const float* __restrict__ bias,
                         int lda, int ldb, int ldc) {
  int tid = threadIdx.x;
  int wave = tid >> 6, lane = tid & 63;
  int wr = wave / WN, wc = wave % WN;
  int rowBase = blockIdx.x * (WM * FM * 16) + wr * FM * 16;
  int colBase = blockIdx.y * (WN * FN * 16) + wc * FN * 16;
  int lr = lane & 15;
  int ko = (lane >> 4) * 8;

  f32x4 acc[FM][FN];
#pragma unroll
  for (int i = 0; i < FM; ++i)
#pragma unroll
    for (int j = 0; j < FN; ++j) acc[i][j] = (f32x4)(0.0f);

#pragma unroll 8
  for (int kk = 0; kk < KK; kk += 32) {
    short8 av[FM], bv[FN];
#pragma unroll
    for (int i = 0; i < FM; ++i)
      av[i] = *reinterpret_cast<const short8*>(A + (long)(rowBase + i * 16 + lr) * lda + kk + ko);
#pragma unroll
    for (int j = 0; j < FN; ++j)
      bv[j] = *reinterpret_cast<const short8*>(Bm + (long)(colBase + j * 16 + lr) * ldb + kk + ko);
#pragma unroll
    for (int i = 0; i < FM; ++i)
#pragma unroll
      for (int j = 0; j < FN; ++j)
        acc[i][j] = __builtin_amdgcn_mfma_f32_16x16x32_bf16(av[i], bv[j], acc[i][j], 0, 0, 0);
  }

  int or0 = (lane >> 4) * 4;
#pragma unroll
  for (int i = 0; i < FM; ++i) {
#pragma unroll
    for (int j = 0; j < FN; ++j) {
      int col = colBase + j * 16 + lr;
      float bval = HAS_BIAS ? bias[col] : 0.f;
#pragma unroll
      for (int r = 0; r < 4; ++r) {
        int row = rowBase + i * 16 + or0 + r;
        float v = acc[i][j][r] + bval;
        if (OUT_BF16)
          ((ushort*)C)[(long)row * ldc + col] = f2bf(v);
        else
          ((float*)C)[(long)row * ldc + col] = v;
      }
    }
  }
}

extern "C" void kernel_launch(void* const* d_in, const int* in_sizes, int n_in,
                              void* d_out, int out_size, void* d_ws, size_t ws_size,
                              hipStream_t stream) {
  const float* x          = (const float*)d_in[0];
  const float* xcent_base = (const float*)d_in[3];
  const float* in_proj_w  = (const float*)d_in[4];
  const float* in_proj_b  = (const float*)d_in[5];
  const float* out_proj_w = (const float*)d_in[6];
  const float* out_proj_b = (const float*)d_in[7];

  char* w = (char*)d_ws;
  ushort* xbC  = (ushort*)(w);                 // 16 MiB
  ushort* xbTC = (ushort*)(w + 16777216);      // 16 MiB
  ushort* PCb  = (ushort*)(w + 33554432);      // 256 KiB
  ushort* wvb  = (ushort*)(w + 33816576);      // 512 KiB
  ushort* wob  = (ushort*)(w + 34340864);      // 512 KiB
  ushort* aout = (ushort*)(w + 34865152);      // 1 MiB

  const float* wq = in_proj_w;
  const float* wk = in_proj_w + 512 * 512;
  const float* wv = in_proj_w + 1024 * 512;
  const float* bq = in_proj_b;
  const float* bv = in_proj_b + 1024;

  prep_all<<<1576, 256, 0, stream>>>(x, wv, out_proj_w, wq, wk, xcent_base, bq,
                                     xbC, xbTC, wvb, wob, PCb,
                                     (float*)d_out + (long)LQ * EMB);

  fused_attn<<<256, 1024, 0, stream>>>(PCb, xbC, xbTC, wvb, bv, aout);

  gemm_abt<512, 1, 2, 2, 2, false, true><<<dim3(32, 8, 1), 256, 0, stream>>>(
      aout, wob, d_out, out_proj_b, 512, 512, 512);
}